// Round 4
// baseline (498.071 us; speedup 1.0000x reference)
//
#include <hip/hip_runtime.h>
#include <cstdint>
#include <cstddef>

typedef unsigned short u16;
typedef __attribute__((ext_vector_type(4))) float f32x4;
typedef __attribute__((ext_vector_type(8))) short bf16x8;

#define AS1 __attribute__((address_space(1)))
#define AS3 __attribute__((address_space(3)))
#define GLDS16(gp, lp) __builtin_amdgcn_global_load_lds((const AS1 void*)(gp), (AS3 void*)(lp), 16, 0, 0)

__device__ __forceinline__ float b2f(u16 u) {
  union { uint32_t i; float f; } v; v.i = ((uint32_t)u) << 16; return v.f;
}
__device__ __forceinline__ u16 f2b(float f) {
  union { float f; uint32_t i; } v; v.f = f;
  uint32_t r = v.i + 0x7fffu + ((v.i >> 16) & 1u);
  return (u16)(r >> 16);
}

// ---------------- fp32 -> bf16 elementwise convert (float4 vectorized) ------
__global__ __launch_bounds__(256) void cvt_f32_bf16(
    const float* __restrict__ in, u16* __restrict__ out, int n4) {
  int i = blockIdx.x * 256 + threadIdx.x;
  if (i >= n4) return;
  float4 v = ((const float4*)in)[i];
  union { u16 s[4]; uint2 u; } o;
  o.s[0] = f2b(v.x); o.s[1] = f2b(v.y); o.s[2] = f2b(v.z); o.s[3] = f2b(v.w);
  ((uint2*)out)[i] = o.u;
}

// ---------------- transpose + convert: out[c][r] = bf16(in[r][c]) -----------
__global__ __launch_bounds__(256) void transpose_f32_bf16(
    const float* __restrict__ in, u16* __restrict__ out, int R, int C) {
  __shared__ u16 t[32][33];
  int bx = blockIdx.x * 32;  // col base
  int by = blockIdx.y * 32;  // row base
  int tx = threadIdx.x & 31, ty = threadIdx.x >> 5;  // ty 0..7
#pragma unroll
  for (int i = 0; i < 4; ++i) {
    int r = by + ty + i * 8;
    t[ty + i * 8][tx] = f2b(in[(size_t)r * C + bx + tx]);
  }
  __syncthreads();
#pragma unroll
  for (int i = 0; i < 4; ++i) {
    int c = bx + ty + i * 8;
    out[(size_t)c * R + by + tx] = t[tx][ty + i * 8];
  }
}

// ---------------- GEMM: C(MxN) = A(MxK) * Bt(NxK)^T, bf16 in, f32 acc -------
// Output bf16 (F32OUT=false) or fp32 (F32OUT=true).
// 128x128 tile, BK=32, 4 waves (2x2), 64x64 per wave, 16x16x32 MFMA.
template <bool F32OUT>
__global__ __launch_bounds__(256) void gemm_bt(
    const u16* __restrict__ A, const u16* __restrict__ Bt, void* __restrict__ Cv,
    int M, int N, int K) {
  __shared__ __align__(16) u16 lA[128 * 32];
  __shared__ __align__(16) u16 lB[128 * 32];
  const int tid = threadIdx.x;
  const int lane = tid & 63, wv = tid >> 6;
  const int g = lane >> 4, lr = lane & 15;
  const int wr = wv >> 1, wc = wv & 1;
  const int bm0 = blockIdx.y * 128, bn0 = blockIdx.x * 128;
  f32x4 acc[4][4] = {};
  const int sr = tid >> 2;          // staging row 0..63
  const int scb = (tid & 3) * 16;   // staging byte col in 64B row
  const u16* ga = A + (size_t)(bm0 + sr) * K + (scb >> 1);
  const u16* gb = Bt + (size_t)(bn0 + sr) * K + (scb >> 1);
  char* dA = (char*)lA + tid * 16;
  char* dB = (char*)lB + tid * 16;
  for (int kt = 0; kt < K; kt += 32) {
    GLDS16(ga + kt, dA);
    GLDS16(ga + (size_t)64 * K + kt, dA + 4096);
    GLDS16(gb + kt, dB);
    GLDS16(gb + (size_t)64 * K + kt, dB + 4096);
    __syncthreads();
    bf16x8 af[4], bfr[4];
#pragma unroll
    for (int m = 0; m < 4; ++m)
      af[m] = *(const bf16x8*)((const char*)lA + (wr * 64 + m * 16 + lr) * 64 + g * 16);
#pragma unroll
    for (int n = 0; n < 4; ++n)
      bfr[n] = *(const bf16x8*)((const char*)lB + (wc * 64 + n * 16 + lr) * 64 + g * 16);
#pragma unroll
    for (int m = 0; m < 4; ++m)
#pragma unroll
      for (int n = 0; n < 4; ++n)
        acc[m][n] = __builtin_amdgcn_mfma_f32_16x16x32_bf16(af[m], bfr[n], acc[m][n], 0, 0, 0);
    __syncthreads();
  }
#pragma unroll
  for (int m = 0; m < 4; ++m)
#pragma unroll
    for (int r = 0; r < 4; ++r) {
      int row = bm0 + wr * 64 + m * 16 + g * 4 + r;
      int col = bn0 + wc * 64 + lr;
      if (F32OUT) {
        float* cp = (float*)Cv + (size_t)row * N + col;
#pragma unroll
        for (int n = 0; n < 4; ++n) cp[n * 16] = acc[m][n][r];
      } else {
        u16* cp = (u16*)Cv + (size_t)row * N + col;
#pragma unroll
        for (int n = 0; n < 4; ++n) cp[n * 16] = f2b(acc[m][n][r]);
      }
    }
}

// ---------------- RoPE + split into Q / K / V^T ----------------
// qkv: (4096 rows) x 3072 bf16. Q: [B][16][S][128]; K: [B][4][S][128];
// Vt: [B][4][128][S]. sin/cos fp32 [S][64].
__global__ __launch_bounds__(256) void rope_split(
    const u16* __restrict__ qkv, const float* __restrict__ sinb,
    const float* __restrict__ cosb, u16* __restrict__ Q, u16* __restrict__ Kb,
    u16* __restrict__ Vt) {
  int row = blockIdx.x;  // 0..4095
  int b = row >> 11, s = row & 2047;
  const u16* src = qkv + (size_t)row * 3072;
  __shared__ float scs[64], scc[64];
  if (threadIdx.x < 64) {
    scs[threadIdx.x] = sinb[s * 64 + threadIdx.x];
    scc[threadIdx.x] = cosb[s * 64 + threadIdx.x];
  }
  __syncthreads();
  int tid = threadIdx.x;
  // Q: 16 heads x 64 pairs
  for (int i = tid; i < 1024; i += 256) {
    int h = i >> 6, d = i & 63;
    float x1 = b2f(src[h * 128 + d]);
    float x2 = b2f(src[h * 128 + 64 + d]);
    size_t o = ((size_t)(b * 16 + h) * 2048 + s) * 128 + d;
    Q[o] = f2b(x1 * scc[d] - x2 * scs[d]);
    Q[o + 64] = f2b(x2 * scc[d] + x1 * scs[d]);
  }
  // K: 4 heads x 64 pairs (exactly 256 work items)
  {
    int i = tid;
    int g2 = i >> 6, d = i & 63;
    float x1 = b2f(src[2048 + g2 * 128 + d]);
    float x2 = b2f(src[2048 + g2 * 128 + 64 + d]);
    size_t o = ((size_t)(b * 4 + g2) * 2048 + s) * 128 + d;
    Kb[o] = f2b(x1 * scc[d] - x2 * scs[d]);
    Kb[o + 64] = f2b(x2 * scc[d] + x1 * scs[d]);
  }
  // V transposed copy: 512 elems
  for (int i = tid; i < 512; i += 256) {
    int g2 = i >> 7, d = i & 127;
    Vt[((size_t)(b * 4 + g2) * 128 + d) * 2048 + s] = src[2560 + g2 * 128 + d];
  }
}

// ---------------- Flash attention with causal + doc mask ----------------
// grid: (S/64, H, B). block 256 = 4 waves; wave handles 16 q rows; KV block 32.
__global__ __launch_bounds__(256) void attn_fwd(
    const u16* __restrict__ Q, const u16* __restrict__ Kb,
    const u16* __restrict__ Vt, const int* __restrict__ doc,
    u16* __restrict__ Out) {
  const int qb = blockIdx.x, h = blockIdx.y, b = blockIdx.z;
  const int gkv = h >> 2;
  const int tid = threadIdx.x, wv = tid >> 6, lane = tid & 63;
  const int g = lane >> 4, lr = lane & 15;
  const float scale = 0.08838834764831845f;  // 1/sqrt(128)
  __shared__ __align__(16) u16 Kl[32 * 128];   // [kv][d]
  __shared__ __align__(16) u16 Vl[128 * 32];   // [d][kv]
  __shared__ __align__(16) u16 Pl[4][16 * 32]; // per-wave P [q][kv]
  const int q0 = qb * 64 + wv * 16;
  // Q fragments (A): lane holds Q[q0+lr][32c + 8g .. +8]
  const u16* qp = Q + ((size_t)(b * 16 + h) * 2048 + q0 + lr) * 128;
  bf16x8 qf[4];
#pragma unroll
  for (int c = 0; c < 4; ++c) qf[c] = *(const bf16x8*)(qp + c * 32 + g * 8);
  int docq[4];
#pragma unroll
  for (int r = 0; r < 4; ++r) docq[r] = doc[b * 2048 + q0 + g * 4 + r];
  float mrow[4] = {-INFINITY, -INFINITY, -INFINITY, -INFINITY};
  float lrow[4] = {0.f, 0.f, 0.f, 0.f};
  f32x4 acc[8] = {};
  const int kv_endb = qb * 64 + 64;
  for (int kv0 = 0; kv0 < kv_endb; kv0 += 32) {
    // stage K (32x128) and Vt (128x32) blocks
#pragma unroll
    for (int it = 0; it < 2; ++it) {
      int ch = tid + it * 256;
      int kr = ch >> 4, kc = (ch & 15) * 16;  // K: 32 rows x 256B
      const u16* gk = Kb + ((size_t)(b * 4 + gkv) * 2048 + kv0 + kr) * 128 + (kc >> 1);
      GLDS16(gk, (char*)Kl + ch * 16);
      int vr = ch >> 2, vc = (ch & 3) * 16;   // V: 128 rows x 64B
      const u16* gv = Vt + ((size_t)(b * 4 + gkv) * 128 + vr) * 2048 + kv0 + (vc >> 1);
      GLDS16(gv, (char*)Vl + ch * 16);
    }
    __syncthreads();
    // scores: two 16-kv halves
    f32x4 s0 = {0.f, 0.f, 0.f, 0.f}, s1 = {0.f, 0.f, 0.f, 0.f};
#pragma unroll
    for (int c = 0; c < 4; ++c) {
      bf16x8 k0 = *(const bf16x8*)((const char*)Kl + (0 * 16 + lr) * 256 + c * 64 + g * 16);
      s0 = __builtin_amdgcn_mfma_f32_16x16x32_bf16(qf[c], k0, s0, 0, 0, 0);
      bf16x8 k1 = *(const bf16x8*)((const char*)Kl + (1 * 16 + lr) * 256 + c * 64 + g * 16);
      s1 = __builtin_amdgcn_mfma_f32_16x16x32_bf16(qf[c], k1, s1, 0, 0, 0);
    }
    int dockv0 = doc[b * 2048 + kv0 + lr];
    int dockv1 = doc[b * 2048 + kv0 + 16 + lr];
#pragma unroll
    for (int r = 0; r < 4; ++r) {
      const int sq = q0 + g * 4 + r;
      int kva = kv0 + lr, kvb = kv0 + 16 + lr;
      float sa = (kva <= sq && dockv0 == docq[r]) ? s0[r] * scale : -INFINITY;
      float sb = (kvb <= sq && dockv1 == docq[r]) ? s1[r] * scale : -INFINITY;
      float rm = fmaxf(sa, sb);
#pragma unroll
      for (int off = 1; off < 16; off <<= 1) rm = fmaxf(rm, __shfl_xor(rm, off, 64));
      float mnew = fmaxf(mrow[r], rm);
      float scf, pa, pb;
      if (mnew == -INFINITY) {
        scf = 1.f; pa = 0.f; pb = 0.f;
      } else {
        scf = expf(mrow[r] - mnew);
        pa = expf(sa - mnew);
        pb = expf(sb - mnew);
      }
      float psum = pa + pb;
#pragma unroll
      for (int off = 1; off < 16; off <<= 1) psum += __shfl_xor(psum, off, 64);
      lrow[r] = lrow[r] * scf + psum;
      mrow[r] = mnew;
#pragma unroll
      for (int chn = 0; chn < 8; ++chn) acc[chn][r] *= scf;
      Pl[wv][(g * 4 + r) * 32 + lr] = f2b(pa);
      Pl[wv][(g * 4 + r) * 32 + 16 + lr] = f2b(pb);
    }
    asm volatile("s_waitcnt lgkmcnt(0)" ::: "memory");
    // PV: A = P[16x32], B = V chunk [32 kv x 16 d] from Vl[d][kv]
    bf16x8 pf = *(const bf16x8*)((const u16*)Pl[wv] + lr * 32 + g * 8);
#pragma unroll
    for (int chn = 0; chn < 8; ++chn) {
      bf16x8 vf = *(const bf16x8*)((const char*)Vl + (chn * 16 + lr) * 64 + g * 16);
      acc[chn] = __builtin_amdgcn_mfma_f32_16x16x32_bf16(pf, vf, acc[chn], 0, 0, 0);
    }
    __syncthreads();
  }
  // epilogue: Out[b][s][h*128 + d]
#pragma unroll
  for (int r = 0; r < 4; ++r) {
    float inv = 1.0f / lrow[r];
    int sq = q0 + g * 4 + r;
    u16* op = Out + ((size_t)b * 2048 + sq) * 2048 + h * 128 + lr;
#pragma unroll
    for (int chn = 0; chn < 8; ++chn) op[chn * 16] = f2b(acc[chn][r] * inv);
  }
}

extern "C" void kernel_launch(void* const* d_in, const int* in_sizes, int n_in,
                              void* d_out, int out_size, void* d_ws, size_t ws_size,
                              hipStream_t stream) {
  const float* x = (const float*)d_in[0];
  const float* sinb = (const float*)d_in[1];
  const float* cosb = (const float*)d_in[2];
  const int* doc = (const int*)d_in[3];
  const float* Wqkv = (const float*)d_in[4];
  const float* Wo = (const float*)d_in[5];

  u16* ws = (u16*)d_ws;
  u16* xb = ws;                             // 8,388,608
  u16* attout = xb;                         // reuse after GEMM1
  u16* WqkvT = ws + 8388608;                // 6,291,456
  u16* WoT = WqkvT;                         // reuse after GEMM1
  u16* qkv = WqkvT + 6291456;               // 12,582,912
  u16* Qb = qkv + 12582912;                 // 8,388,608
  u16* Kb = Qb + 8388608;                   // 2,097,152
  u16* Vt = Kb + 2097152;                   // 2,097,152
  // total: 39,845,888 u16 = ~79.7 MB

  cvt_f32_bf16<<<8388608 / 4 / 256, 256, 0, stream>>>(x, xb, 8388608 / 4);
  transpose_f32_bf16<<<dim3(3072 / 32, 2048 / 32), 256, 0, stream>>>(Wqkv, WqkvT, 2048, 3072);
  gemm_bt<false><<<dim3(3072 / 128, 4096 / 128), 256, 0, stream>>>(xb, WqkvT, qkv, 4096, 3072, 2048);
  transpose_f32_bf16<<<dim3(2048 / 32, 2048 / 32), 256, 0, stream>>>(Wo, WoT, 2048, 2048);
  rope_split<<<4096, 256, 0, stream>>>(qkv, sinb, cosb, Qb, Kb, Vt);
  attn_fwd<<<dim3(2048 / 64, 16, 2), 256, 0, stream>>>(Qb, Kb, Vt, doc, attout);
  gemm_bt<true><<<dim3(2048 / 128, 4096 / 128), 256, 0, stream>>>(attout, WoT, (float*)d_out, 4096, 2048, 2048);
}

// Round 5
// 323.912 us; speedup vs baseline: 1.5377x; 1.5377x over previous
//
#include <hip/hip_runtime.h>
#include <cstdint>
#include <cstddef>

typedef unsigned short u16;
typedef __attribute__((ext_vector_type(4))) float f32x4;
typedef __attribute__((ext_vector_type(8))) short bf16x8;

#define AS1 __attribute__((address_space(1)))
#define AS3 __attribute__((address_space(3)))
#define GLDS16(gp, lp) __builtin_amdgcn_global_load_lds((const AS1 void*)(gp), (AS3 void*)(lp), 16, 0, 0)

__device__ __forceinline__ float b2f(u16 u) {
  union { uint32_t i; float f; } v; v.i = ((uint32_t)u) << 16; return v.f;
}
__device__ __forceinline__ u16 f2b(float f) {
  union { float f; uint32_t i; } v; v.f = f;
  uint32_t r = v.i + 0x7fffu + ((v.i >> 16) & 1u);
  return (u16)(r >> 16);
}

// ---------------- fp32 -> bf16 elementwise convert (float4 vectorized) ------
__global__ __launch_bounds__(256) void cvt_f32_bf16(
    const float* __restrict__ in, u16* __restrict__ out, int n4) {
  int i = blockIdx.x * 256 + threadIdx.x;
  if (i >= n4) return;
  float4 v = ((const float4*)in)[i];
  union { u16 s[4]; uint2 u; } o;
  o.s[0] = f2b(v.x); o.s[1] = f2b(v.y); o.s[2] = f2b(v.z); o.s[3] = f2b(v.w);
  ((uint2*)out)[i] = o.u;
}

// ---------------- transpose + convert: out[c][r] = bf16(in[r][c]) -----------
__global__ __launch_bounds__(256) void transpose_f32_bf16(
    const float* __restrict__ in, u16* __restrict__ out, int R, int C) {
  __shared__ u16 t[32][33];
  int bx = blockIdx.x * 32;  // col base
  int by = blockIdx.y * 32;  // row base
  int tx = threadIdx.x & 31, ty = threadIdx.x >> 5;  // ty 0..7
#pragma unroll
  for (int i = 0; i < 4; ++i) {
    int r = by + ty + i * 8;
    t[ty + i * 8][tx] = f2b(in[(size_t)r * C + bx + tx]);
  }
  __syncthreads();
#pragma unroll
  for (int i = 0; i < 4; ++i) {
    int c = bx + ty + i * 8;
    out[(size_t)c * R + by + tx] = t[tx][ty + i * 8];
  }
}

// ---------------- GEMM: C(MxN) = A(MxK) * Bt(NxK)^T, bf16 in, f32 acc -------
// Output bf16 (F32OUT=false) or fp32 (F32OUT=true).
// 128x128 tile, BK=32, 4 waves (2x2), 64x64 per wave, 16x16x32 MFMA.
template <bool F32OUT>
__global__ __launch_bounds__(256) void gemm_bt(
    const u16* __restrict__ A, const u16* __restrict__ Bt, void* __restrict__ Cv,
    int M, int N, int K) {
  __shared__ __align__(16) u16 lA[128 * 32];
  __shared__ __align__(16) u16 lB[128 * 32];
  const int tid = threadIdx.x;
  const int lane = tid & 63, wv = tid >> 6;
  const int g = lane >> 4, lr = lane & 15;
  const int wr = wv >> 1, wc = wv & 1;
  const int bm0 = blockIdx.y * 128, bn0 = blockIdx.x * 128;
  f32x4 acc[4][4] = {};
  const int sr = tid >> 2;          // staging row 0..63
  const int scb = (tid & 3) * 16;   // staging byte col in 64B row
  const u16* ga = A + (size_t)(bm0 + sr) * K + (scb >> 1);
  const u16* gb = Bt + (size_t)(bn0 + sr) * K + (scb >> 1);
  char* dA = (char*)lA + tid * 16;
  char* dB = (char*)lB + tid * 16;
  for (int kt = 0; kt < K; kt += 32) {
    GLDS16(ga + kt, dA);
    GLDS16(ga + (size_t)64 * K + kt, dA + 4096);
    GLDS16(gb + kt, dB);
    GLDS16(gb + (size_t)64 * K + kt, dB + 4096);
    __syncthreads();
    bf16x8 af[4], bfr[4];
#pragma unroll
    for (int m = 0; m < 4; ++m)
      af[m] = *(const bf16x8*)((const char*)lA + (wr * 64 + m * 16 + lr) * 64 + g * 16);
#pragma unroll
    for (int n = 0; n < 4; ++n)
      bfr[n] = *(const bf16x8*)((const char*)lB + (wc * 64 + n * 16 + lr) * 64 + g * 16);
#pragma unroll
    for (int m = 0; m < 4; ++m)
#pragma unroll
      for (int n = 0; n < 4; ++n)
        acc[m][n] = __builtin_amdgcn_mfma_f32_16x16x32_bf16(af[m], bfr[n], acc[m][n], 0, 0, 0);
    __syncthreads();
  }
#pragma unroll
  for (int m = 0; m < 4; ++m)
#pragma unroll
    for (int r = 0; r < 4; ++r) {
      int row = bm0 + wr * 64 + m * 16 + g * 4 + r;
      int col = bn0 + wc * 64 + lr;
      if (F32OUT) {
        float* cp = (float*)Cv + (size_t)row * N + col;
#pragma unroll
        for (int n = 0; n < 4; ++n) cp[n * 16] = acc[m][n][r];
      } else {
        u16* cp = (u16*)Cv + (size_t)row * N + col;
#pragma unroll
        for (int n = 0; n < 4; ++n) cp[n * 16] = f2b(acc[m][n][r]);
      }
    }
}

// ---------------- RoPE + split into Q / K / V^T ----------------
// qkv: (4096 rows) x 3072 bf16. Q: [B][16][S][128]; K: [B][4][S][128];
// Vt: [B][4][128][S]. sin/cos fp32 [S][64].
__global__ __launch_bounds__(256) void rope_split(
    const u16* __restrict__ qkv, const float* __restrict__ sinb,
    const float* __restrict__ cosb, u16* __restrict__ Q, u16* __restrict__ Kb,
    u16* __restrict__ Vt) {
  int row = blockIdx.x;  // 0..4095
  int b = row >> 11, s = row & 2047;
  const u16* src = qkv + (size_t)row * 3072;
  __shared__ float scs[64], scc[64];
  if (threadIdx.x < 64) {
    scs[threadIdx.x] = sinb[s * 64 + threadIdx.x];
    scc[threadIdx.x] = cosb[s * 64 + threadIdx.x];
  }
  __syncthreads();
  int tid = threadIdx.x;
  // Q: 16 heads x 64 pairs
  for (int i = tid; i < 1024; i += 256) {
    int h = i >> 6, d = i & 63;
    float x1 = b2f(src[h * 128 + d]);
    float x2 = b2f(src[h * 128 + 64 + d]);
    size_t o = ((size_t)(b * 16 + h) * 2048 + s) * 128 + d;
    Q[o] = f2b(x1 * scc[d] - x2 * scs[d]);
    Q[o + 64] = f2b(x2 * scc[d] + x1 * scs[d]);
  }
  // K: 4 heads x 64 pairs (exactly 256 work items)
  {
    int i = tid;
    int g2 = i >> 6, d = i & 63;
    float x1 = b2f(src[2048 + g2 * 128 + d]);
    float x2 = b2f(src[2048 + g2 * 128 + 64 + d]);
    size_t o = ((size_t)(b * 4 + g2) * 2048 + s) * 128 + d;
    Kb[o] = f2b(x1 * scc[d] - x2 * scs[d]);
    Kb[o + 64] = f2b(x2 * scc[d] + x1 * scs[d]);
  }
  // V transposed copy: 512 elems
  for (int i = tid; i < 512; i += 256) {
    int g2 = i >> 7, d = i & 127;
    Vt[((size_t)(b * 4 + g2) * 128 + d) * 2048 + s] = src[2560 + g2 * 128 + d];
  }
}

// ---------------- Flash attention with causal + doc mask ----------------
// grid: (16, H, B). Each block processes q-tiles qpair and 31-qpair (64 rows
// each) -> every block does exactly 33 KV tiles (load balance).
// block 256 = 4 waves; wave handles 16 q rows; KV block 32.
// K in LDS: linear dest, XOR-swizzled content (chunk ^= row&7), conflict-free.
// V/P in LDS: 80B padded rows, conflict-free.
__global__ __launch_bounds__(256) void attn_fwd(
    const u16* __restrict__ Q, const u16* __restrict__ Kb,
    const u16* __restrict__ Vt, const int* __restrict__ doc,
    u16* __restrict__ Out) {
  const int qpair = blockIdx.x, h = blockIdx.y, b = blockIdx.z;
  const int gkv = h >> 2;
  const int tid = threadIdx.x, wv = tid >> 6, lane = tid & 63;
  const int g = lane >> 4, lr = lane & 15;
  const float scale = 0.08838834764831845f;  // 1/sqrt(128)
  __shared__ __align__(16) u16 Kl[32 * 128];   // [kv][d], swizzled chunks
  __shared__ __align__(16) u16 Vl[128 * 40];   // [d][kv], 80B rows (64B+16B pad)
  __shared__ __align__(16) u16 Pl[4][16 * 40]; // per-wave P, 80B rows
  const u16* Kbase = Kb + (size_t)(b * 4 + gkv) * 2048 * 128;
  const u16* Vbase = Vt + (size_t)(b * 4 + gkv) * 128 * 2048;

  for (int pass = 0; pass < 2; ++pass) {
    const int qb = pass ? (31 - qpair) : qpair;
    const int q0 = qb * 64 + wv * 16;
    // Q fragments (A): lane holds Q[q0+lr][32c + 8g .. +8]
    const u16* qp = Q + ((size_t)(b * 16 + h) * 2048 + q0 + lr) * 128;
    bf16x8 qf[4];
#pragma unroll
    for (int c = 0; c < 4; ++c) qf[c] = *(const bf16x8*)(qp + c * 32 + g * 8);
    int docq[4];
#pragma unroll
    for (int r = 0; r < 4; ++r) docq[r] = doc[b * 2048 + q0 + g * 4 + r];
    float mrow[4] = {-INFINITY, -INFINITY, -INFINITY, -INFINITY};
    float lrow[4] = {0.f, 0.f, 0.f, 0.f};
    f32x4 acc[8] = {};
    const int kv_end = qb * 64 + 64;
    for (int kv0 = 0; kv0 < kv_end; kv0 += 32) {
      // --- stage K (32x128) via global_load_lds, source pre-swizzled ---
#pragma unroll
      for (int it = 0; it < 2; ++it) {
        int ch = tid + it * 256;
        int kr = ch >> 4, j = ch & 15;  // row, 16B-chunk
        GLDS16(Kbase + (size_t)(kv0 + kr) * 128 + ((j ^ (kr & 7)) << 3),
               (char*)Kl + ch * 16);
      }
      // --- stage V (128d x 32kv) via regs into padded LDS ---
      bf16x8 vreg[2];
#pragma unroll
      for (int it = 0; it < 2; ++it) {
        int unit = tid + it * 256;
        int d = unit >> 2, c = unit & 3;
        vreg[it] = *(const bf16x8*)(Vbase + (size_t)d * 2048 + kv0 + c * 8);
      }
#pragma unroll
      for (int it = 0; it < 2; ++it) {
        int unit = tid + it * 256;
        int d = unit >> 2, c = unit & 3;
        *(bf16x8*)((char*)Vl + d * 80 + c * 16) = vreg[it];
      }
      __syncthreads();
      // --- scores: two 16-kv halves, swizzled K reads ---
      f32x4 s0 = {0.f, 0.f, 0.f, 0.f}, s1 = {0.f, 0.f, 0.f, 0.f};
      __builtin_amdgcn_s_setprio(1);
#pragma unroll
      for (int c = 0; c < 4; ++c) {
        int chnk = ((c * 4 + g) ^ (lr & 7)) << 4;
        bf16x8 k0 = *(const bf16x8*)((const char*)Kl + lr * 256 + chnk);
        s0 = __builtin_amdgcn_mfma_f32_16x16x32_bf16(qf[c], k0, s0, 0, 0, 0);
        bf16x8 k1 = *(const bf16x8*)((const char*)Kl + (16 + lr) * 256 + chnk);
        s1 = __builtin_amdgcn_mfma_f32_16x16x32_bf16(qf[c], k1, s1, 0, 0, 0);
      }
      __builtin_amdgcn_s_setprio(0);
      int dockv0 = doc[b * 2048 + kv0 + lr];
      int dockv1 = doc[b * 2048 + kv0 + 16 + lr];
#pragma unroll
      for (int r = 0; r < 4; ++r) {
        const int sq = q0 + g * 4 + r;
        int kva = kv0 + lr, kvb = kv0 + 16 + lr;
        float sa = (kva <= sq && dockv0 == docq[r]) ? s0[r] * scale : -INFINITY;
        float sb = (kvb <= sq && dockv1 == docq[r]) ? s1[r] * scale : -INFINITY;
        float rm = fmaxf(sa, sb);
#pragma unroll
        for (int off = 1; off < 16; off <<= 1) rm = fmaxf(rm, __shfl_xor(rm, off, 64));
        float mnew = fmaxf(mrow[r], rm);
        float scf, pa, pb;
        if (mnew == -INFINITY) {
          scf = 1.f; pa = 0.f; pb = 0.f;
        } else {
          scf = expf(mrow[r] - mnew);
          pa = expf(sa - mnew);
          pb = expf(sb - mnew);
        }
        float psum = pa + pb;
#pragma unroll
        for (int off = 1; off < 16; off <<= 1) psum += __shfl_xor(psum, off, 64);
        lrow[r] = lrow[r] * scf + psum;
        mrow[r] = mnew;
#pragma unroll
        for (int chn = 0; chn < 8; ++chn) acc[chn][r] *= scf;
        Pl[wv][(g * 4 + r) * 40 + lr] = f2b(pa);
        Pl[wv][(g * 4 + r) * 40 + 16 + lr] = f2b(pb);
      }
      asm volatile("s_waitcnt lgkmcnt(0)" ::: "memory");
      // PV: A = P[16x32], B = V chunk [32 kv x 16 d] from padded Vl[d][kv]
      bf16x8 pf = *(const bf16x8*)((const u16*)Pl[wv] + lr * 40 + g * 8);
      __builtin_amdgcn_s_setprio(1);
#pragma unroll
      for (int chn = 0; chn < 8; ++chn) {
        bf16x8 vf = *(const bf16x8*)((const char*)Vl + (chn * 16 + lr) * 80 + g * 16);
        acc[chn] = __builtin_amdgcn_mfma_f32_16x16x32_bf16(pf, vf, acc[chn], 0, 0, 0);
      }
      __builtin_amdgcn_s_setprio(0);
      __syncthreads();
    }
    // epilogue: Out[b][s][h*128 + d]
#pragma unroll
    for (int r = 0; r < 4; ++r) {
      float inv = 1.0f / lrow[r];
      int sq = q0 + g * 4 + r;
      u16* op = Out + ((size_t)b * 2048 + sq) * 2048 + h * 128 + lr;
#pragma unroll
      for (int chn = 0; chn < 8; ++chn) op[chn * 16] = f2b(acc[chn][r] * inv);
    }
  }
}

extern "C" void kernel_launch(void* const* d_in, const int* in_sizes, int n_in,
                              void* d_out, int out_size, void* d_ws, size_t ws_size,
                              hipStream_t stream) {
  const float* x = (const float*)d_in[0];
  const float* sinb = (const float*)d_in[1];
  const float* cosb = (const float*)d_in[2];
  const int* doc = (const int*)d_in[3];
  const float* Wqkv = (const float*)d_in[4];
  const float* Wo = (const float*)d_in[5];

  u16* ws = (u16*)d_ws;
  u16* xb = ws;                             // 8,388,608
  u16* attout = xb;                         // reuse after GEMM1
  u16* WqkvT = ws + 8388608;                // 6,291,456
  u16* WoT = WqkvT;                         // reuse after GEMM1
  u16* qkv = WqkvT + 6291456;               // 12,582,912
  u16* Qb = qkv + 12582912;                 // 8,388,608
  u16* Kb = Qb + 8388608;                   // 2,097,152
  u16* Vt = Kb + 2097152;                   // 2,097,152
  // total: 39,845,888 u16 = ~79.7 MB

  cvt_f32_bf16<<<8388608 / 4 / 256, 256, 0, stream>>>(x, xb, 8388608 / 4);
  transpose_f32_bf16<<<dim3(3072 / 32, 2048 / 32), 256, 0, stream>>>(Wqkv, WqkvT, 2048, 3072);
  gemm_bt<false><<<dim3(3072 / 128, 4096 / 128), 256, 0, stream>>>(xb, WqkvT, qkv, 4096, 3072, 2048);
  transpose_f32_bf16<<<dim3(2048 / 32, 2048 / 32), 256, 0, stream>>>(Wo, WoT, 2048, 2048);
  rope_split<<<4096, 256, 0, stream>>>(qkv, sinb, cosb, Qb, Kb, Vt);
  attn_fwd<<<dim3(16, 16, 2), 256, 0, stream>>>(Qb, Kb, Vt, doc, attout);
  gemm_bt<true><<<dim3(2048 / 128, 4096 / 128), 256, 0, stream>>>(attout, WoT, (float*)d_out, 4096, 2048, 2048);
}

// Round 6
// 259.843 us; speedup vs baseline: 1.9168x; 1.2466x over previous
//
#include <hip/hip_runtime.h>
#include <cstdint>
#include <cstddef>

typedef unsigned short u16;
typedef __attribute__((ext_vector_type(4))) float f32x4;
typedef __attribute__((ext_vector_type(8))) short bf16x8;

#define AS1 __attribute__((address_space(1)))
#define AS3 __attribute__((address_space(3)))
#define GLDS16(gp, lp) __builtin_amdgcn_global_load_lds((const AS1 void*)(gp), (AS3 void*)(lp), 16, 0, 0)

__device__ __forceinline__ float b2f(u16 u) {
  union { uint32_t i; float f; } v; v.i = ((uint32_t)u) << 16; return v.f;
}
__device__ __forceinline__ u16 f2b(float f) {
  union { float f; uint32_t i; } v; v.f = f;
  uint32_t r = v.i + 0x7fffu + ((v.i >> 16) & 1u);
  return (u16)(r >> 16);
}

// ---------------- fp32 -> bf16 elementwise convert (float4 vectorized) ------
__global__ __launch_bounds__(256) void cvt_f32_bf16(
    const float* __restrict__ in, u16* __restrict__ out, int n4) {
  int i = blockIdx.x * 256 + threadIdx.x;
  if (i >= n4) return;
  float4 v = ((const float4*)in)[i];
  union { u16 s[4]; uint2 u; } o;
  o.s[0] = f2b(v.x); o.s[1] = f2b(v.y); o.s[2] = f2b(v.z); o.s[3] = f2b(v.w);
  ((uint2*)out)[i] = o.u;
}

// ---------------- transpose + convert: out[c][r] = bf16(in[r][c]) -----------
__global__ __launch_bounds__(256) void transpose_f32_bf16(
    const float* __restrict__ in, u16* __restrict__ out, int R, int C) {
  __shared__ u16 t[32][33];
  int bx = blockIdx.x * 32;  // col base
  int by = blockIdx.y * 32;  // row base
  int tx = threadIdx.x & 31, ty = threadIdx.x >> 5;  // ty 0..7
#pragma unroll
  for (int i = 0; i < 4; ++i) {
    int r = by + ty + i * 8;
    t[ty + i * 8][tx] = f2b(in[(size_t)r * C + bx + tx]);
  }
  __syncthreads();
#pragma unroll
  for (int i = 0; i < 4; ++i) {
    int c = bx + ty + i * 8;
    out[(size_t)c * R + by + tx] = t[tx][ty + i * 8];
  }
}

// ---------------- doc start table: ds[b*4+d] = first s with doc==d ----------
__global__ __launch_bounds__(256) void doc_starts(
    const int* __restrict__ doc, int* __restrict__ ds) {
  int i = blockIdx.x * 256 + threadIdx.x;  // 0..4095
  if (i >= 4096) return;
  int b = i >> 11, s = i & 2047;
  int d = doc[i];
  if (s == 0 || doc[i - 1] != d) atomicMin(&ds[b * 4 + d], s);
}

// ---------------- GEMM: C(MxN) = A(MxK) * Bt(NxK)^T, bf16 in, f32 acc -------
// Output bf16 (F32OUT=false) or fp32 (F32OUT=true).
// 128x128 tile, BK=32, 4 waves (2x2), 64x64 per wave, 16x16x32 MFMA.
template <bool F32OUT>
__global__ __launch_bounds__(256) void gemm_bt(
    const u16* __restrict__ A, const u16* __restrict__ Bt, void* __restrict__ Cv,
    int M, int N, int K) {
  __shared__ __align__(16) u16 lA[128 * 32];
  __shared__ __align__(16) u16 lB[128 * 32];
  const int tid = threadIdx.x;
  const int lane = tid & 63, wv = tid >> 6;
  const int g = lane >> 4, lr = lane & 15;
  const int wr = wv >> 1, wc = wv & 1;
  const int bm0 = blockIdx.y * 128, bn0 = blockIdx.x * 128;
  f32x4 acc[4][4] = {};
  const int sr = tid >> 2;          // staging row 0..63
  const int scb = (tid & 3) * 16;   // staging byte col in 64B row
  const u16* ga = A + (size_t)(bm0 + sr) * K + (scb >> 1);
  const u16* gb = Bt + (size_t)(bn0 + sr) * K + (scb >> 1);
  char* dA = (char*)lA + tid * 16;
  char* dB = (char*)lB + tid * 16;
  for (int kt = 0; kt < K; kt += 32) {
    GLDS16(ga + kt, dA);
    GLDS16(ga + (size_t)64 * K + kt, dA + 4096);
    GLDS16(gb + kt, dB);
    GLDS16(gb + (size_t)64 * K + kt, dB + 4096);
    __syncthreads();
    bf16x8 af[4], bfr[4];
#pragma unroll
    for (int m = 0; m < 4; ++m)
      af[m] = *(const bf16x8*)((const char*)lA + (wr * 64 + m * 16 + lr) * 64 + g * 16);
#pragma unroll
    for (int n = 0; n < 4; ++n)
      bfr[n] = *(const bf16x8*)((const char*)lB + (wc * 64 + n * 16 + lr) * 64 + g * 16);
#pragma unroll
    for (int m = 0; m < 4; ++m)
#pragma unroll
      for (int n = 0; n < 4; ++n)
        acc[m][n] = __builtin_amdgcn_mfma_f32_16x16x32_bf16(af[m], bfr[n], acc[m][n], 0, 0, 0);
    __syncthreads();
  }
#pragma unroll
  for (int m = 0; m < 4; ++m)
#pragma unroll
    for (int r = 0; r < 4; ++r) {
      int row = bm0 + wr * 64 + m * 16 + g * 4 + r;
      int col = bn0 + wc * 64 + lr;
      if (F32OUT) {
        float* cp = (float*)Cv + (size_t)row * N + col;
#pragma unroll
        for (int n = 0; n < 4; ++n) cp[n * 16] = acc[m][n][r];
      } else {
        u16* cp = (u16*)Cv + (size_t)row * N + col;
#pragma unroll
        for (int n = 0; n < 4; ++n) cp[n * 16] = f2b(acc[m][n][r]);
      }
    }
}

// ---------------- RoPE + split into Q / K / V^T ----------------
// qkv: (4096 rows) x 3072 bf16. Q: [B][16][S][128]; K: [B][4][S][128];
// Vt: [B][4][128][S]. sin/cos fp32 [S][64].
__global__ __launch_bounds__(256) void rope_split(
    const u16* __restrict__ qkv, const float* __restrict__ sinb,
    const float* __restrict__ cosb, u16* __restrict__ Q, u16* __restrict__ Kb,
    u16* __restrict__ Vt) {
  int row = blockIdx.x;  // 0..4095
  int b = row >> 11, s = row & 2047;
  const u16* src = qkv + (size_t)row * 3072;
  __shared__ float scs[64], scc[64];
  if (threadIdx.x < 64) {
    scs[threadIdx.x] = sinb[s * 64 + threadIdx.x];
    scc[threadIdx.x] = cosb[s * 64 + threadIdx.x];
  }
  __syncthreads();
  int tid = threadIdx.x;
  // Q: 16 heads x 64 pairs
  for (int i = tid; i < 1024; i += 256) {
    int h = i >> 6, d = i & 63;
    float x1 = b2f(src[h * 128 + d]);
    float x2 = b2f(src[h * 128 + 64 + d]);
    size_t o = ((size_t)(b * 16 + h) * 2048 + s) * 128 + d;
    Q[o] = f2b(x1 * scc[d] - x2 * scs[d]);
    Q[o + 64] = f2b(x2 * scc[d] + x1 * scs[d]);
  }
  // K: 4 heads x 64 pairs (exactly 256 work items)
  {
    int i = tid;
    int g2 = i >> 6, d = i & 63;
    float x1 = b2f(src[2048 + g2 * 128 + d]);
    float x2 = b2f(src[2048 + g2 * 128 + 64 + d]);
    size_t o = ((size_t)(b * 4 + g2) * 2048 + s) * 128 + d;
    Kb[o] = f2b(x1 * scc[d] - x2 * scs[d]);
    Kb[o + 64] = f2b(x2 * scc[d] + x1 * scs[d]);
  }
  // V transposed copy: 512 elems
  for (int i = tid; i < 512; i += 256) {
    int g2 = i >> 7, d = i & 127;
    Vt[((size_t)(b * 4 + g2) * 128 + d) * 2048 + s] = src[2560 + g2 * 128 + d];
  }
}

// ---------------- Flash attention with causal + doc mask ----------------
// grid: (16, H, B). Each block processes q-tiles qpair and 31-qpair (64 rows
// each). Doc-sorted skip: kv tiles before the start of the tile's first doc
// are fully masked -> start loop at doc_start (rounded to 32).
// block 256 = 4 waves; wave handles 16 q rows; KV block 32.
// K in LDS: linear dest, XOR-swizzled content (chunk ^= row&7), conflict-free.
// V/P in LDS: 80B padded rows, conflict-free.
__global__ __launch_bounds__(256) void attn_fwd(
    const u16* __restrict__ Q, const u16* __restrict__ Kb,
    const u16* __restrict__ Vt, const int* __restrict__ doc,
    const int* __restrict__ dstab, u16* __restrict__ Out) {
  const int qpair = blockIdx.x, h = blockIdx.y, b = blockIdx.z;
  const int gkv = h >> 2;
  const int tid = threadIdx.x, wv = tid >> 6, lane = tid & 63;
  const int g = lane >> 4, lr = lane & 15;
  const float scale = 0.08838834764831845f;  // 1/sqrt(128)
  __shared__ __align__(16) u16 Kl[32 * 128];   // [kv][d], swizzled chunks
  __shared__ __align__(16) u16 Vl[128 * 40];   // [d][kv], 80B rows (64B+16B pad)
  __shared__ __align__(16) u16 Pl[4][16 * 40]; // per-wave P, 80B rows
  const u16* Kbase = Kb + (size_t)(b * 4 + gkv) * 2048 * 128;
  const u16* Vbase = Vt + (size_t)(b * 4 + gkv) * 128 * 2048;
  const int b2048 = b * 2048;

  for (int pass = 0; pass < 2; ++pass) {
    const int qb = pass ? (31 - qpair) : qpair;
    const int q0 = qb * 64 + wv * 16;
    // Q fragments (A): lane holds Q[q0+lr][32c + 8g .. +8]
    const u16* qp = Q + ((size_t)(b * 16 + h) * 2048 + q0 + lr) * 128;
    bf16x8 qf[4];
#pragma unroll
    for (int c = 0; c < 4; ++c) qf[c] = *(const bf16x8*)(qp + c * 32 + g * 8);
    int docq[4];
#pragma unroll
    for (int r = 0; r < 4; ++r) docq[r] = doc[b2048 + q0 + g * 4 + r];
    float mrow[4] = {-INFINITY, -INFINITY, -INFINITY, -INFINITY};
    float lrow[4] = {0.f, 0.f, 0.f, 0.f};
    f32x4 acc[8] = {};
    // doc-sorted skip: all kv < start(doc of block's first row) are masked
    const int kv_lo = dstab[b * 4 + doc[b2048 + qb * 64]] & ~31;
    const int kv_end = qb * 64 + 64;
    for (int kv0 = kv_lo; kv0 < kv_end; kv0 += 32) {
      // --- stage K (32x128) via global_load_lds, source pre-swizzled ---
#pragma unroll
      for (int it = 0; it < 2; ++it) {
        int ch = tid + it * 256;
        int kr = ch >> 4, j = ch & 15;  // row, 16B-chunk
        GLDS16(Kbase + (size_t)(kv0 + kr) * 128 + ((j ^ (kr & 7)) << 3),
               (char*)Kl + ch * 16);
      }
      // --- stage V (128d x 32kv) via regs into padded LDS ---
      bf16x8 vreg[2];
#pragma unroll
      for (int it = 0; it < 2; ++it) {
        int unit = tid + it * 256;
        int d = unit >> 2, c = unit & 3;
        vreg[it] = *(const bf16x8*)(Vbase + (size_t)d * 2048 + kv0 + c * 8);
      }
#pragma unroll
      for (int it = 0; it < 2; ++it) {
        int unit = tid + it * 256;
        int d = unit >> 2, c = unit & 3;
        *(bf16x8*)((char*)Vl + d * 80 + c * 16) = vreg[it];
      }
      __syncthreads();
      // --- scores: two 16-kv halves, swizzled K reads ---
      f32x4 s0 = {0.f, 0.f, 0.f, 0.f}, s1 = {0.f, 0.f, 0.f, 0.f};
      __builtin_amdgcn_s_setprio(1);
#pragma unroll
      for (int c = 0; c < 4; ++c) {
        int chnk = ((c * 4 + g) ^ (lr & 7)) << 4;
        bf16x8 k0 = *(const bf16x8*)((const char*)Kl + lr * 256 + chnk);
        s0 = __builtin_amdgcn_mfma_f32_16x16x32_bf16(qf[c], k0, s0, 0, 0, 0);
        bf16x8 k1 = *(const bf16x8*)((const char*)Kl + (16 + lr) * 256 + chnk);
        s1 = __builtin_amdgcn_mfma_f32_16x16x32_bf16(qf[c], k1, s1, 0, 0, 0);
      }
      __builtin_amdgcn_s_setprio(0);
      int dockv0 = doc[b2048 + kv0 + lr];
      int dockv1 = doc[b2048 + kv0 + 16 + lr];
#pragma unroll
      for (int r = 0; r < 4; ++r) {
        const int sq = q0 + g * 4 + r;
        int kva = kv0 + lr, kvb = kv0 + 16 + lr;
        float sa = (kva <= sq && dockv0 == docq[r]) ? s0[r] * scale : -INFINITY;
        float sb = (kvb <= sq && dockv1 == docq[r]) ? s1[r] * scale : -INFINITY;
        float rm = fmaxf(sa, sb);
#pragma unroll
        for (int off = 1; off < 16; off <<= 1) rm = fmaxf(rm, __shfl_xor(rm, off, 64));
        float mnew = fmaxf(mrow[r], rm);
        float scf, pa, pb;
        if (mnew == -INFINITY) {
          scf = 1.f; pa = 0.f; pb = 0.f;
        } else {
          scf = __expf(mrow[r] - mnew);
          pa = __expf(sa - mnew);
          pb = __expf(sb - mnew);
        }
        float psum = pa + pb;
#pragma unroll
        for (int off = 1; off < 16; off <<= 1) psum += __shfl_xor(psum, off, 64);
        lrow[r] = lrow[r] * scf + psum;
        mrow[r] = mnew;
#pragma unroll
        for (int chn = 0; chn < 8; ++chn) acc[chn][r] *= scf;
        Pl[wv][(g * 4 + r) * 40 + lr] = f2b(pa);
        Pl[wv][(g * 4 + r) * 40 + 16 + lr] = f2b(pb);
      }
      asm volatile("s_waitcnt lgkmcnt(0)" ::: "memory");
      // PV: A = P[16x32], B = V chunk [32 kv x 16 d] from padded Vl[d][kv]
      bf16x8 pf = *(const bf16x8*)((const u16*)Pl[wv] + lr * 40 + g * 8);
      __builtin_amdgcn_s_setprio(1);
#pragma unroll
      for (int chn = 0; chn < 8; ++chn) {
        bf16x8 vf = *(const bf16x8*)((const char*)Vl + (chn * 16 + lr) * 80 + g * 16);
        acc[chn] = __builtin_amdgcn_mfma_f32_16x16x32_bf16(pf, vf, acc[chn], 0, 0, 0);
      }
      __builtin_amdgcn_s_setprio(0);
      __syncthreads();
    }
    // epilogue: Out[b][s][h*128 + d]
#pragma unroll
    for (int r = 0; r < 4; ++r) {
      float inv = 1.0f / lrow[r];
      int sq = q0 + g * 4 + r;
      u16* op = Out + ((size_t)b2048 + sq) * 2048 + h * 128 + lr;
#pragma unroll
      for (int chn = 0; chn < 8; ++chn) op[chn * 16] = f2b(acc[chn][r] * inv);
    }
  }
}

extern "C" void kernel_launch(void* const* d_in, const int* in_sizes, int n_in,
                              void* d_out, int out_size, void* d_ws, size_t ws_size,
                              hipStream_t stream) {
  const float* x = (const float*)d_in[0];
  const float* sinb = (const float*)d_in[1];
  const float* cosb = (const float*)d_in[2];
  const int* doc = (const int*)d_in[3];
  const float* Wqkv = (const float*)d_in[4];
  const float* Wo = (const float*)d_in[5];

  u16* ws = (u16*)d_ws;
  u16* xb = ws;                             // 8,388,608
  u16* attout = xb;                         // reuse after GEMM1
  u16* WqkvT = ws + 8388608;                // 6,291,456
  u16* WoT = WqkvT;                         // reuse after GEMM1
  u16* qkv = WqkvT + 6291456;               // 12,582,912
  u16* Qb = qkv + 12582912;                 // 8,388,608
  u16* Kb = Qb + 8388608;                   // 2,097,152
  u16* Vt = Kb + 2097152;                   // 2,097,152
  int* dstab = (int*)(ws + 39845888);       // 8 ints
  // total: ~79.7 MB + 32B

  hipMemsetAsync(dstab, 0x7f, 8 * sizeof(int), stream);
  doc_starts<<<16, 256, 0, stream>>>(doc, dstab);
  cvt_f32_bf16<<<8388608 / 4 / 256, 256, 0, stream>>>(x, xb, 8388608 / 4);
  transpose_f32_bf16<<<dim3(3072 / 32, 2048 / 32), 256, 0, stream>>>(Wqkv, WqkvT, 2048, 3072);
  gemm_bt<false><<<dim3(3072 / 128, 4096 / 128), 256, 0, stream>>>(xb, WqkvT, qkv, 4096, 3072, 2048);
  transpose_f32_bf16<<<dim3(2048 / 32, 2048 / 32), 256, 0, stream>>>(Wo, WoT, 2048, 2048);
  rope_split<<<4096, 256, 0, stream>>>(qkv, sinb, cosb, Qb, Kb, Vt);
  attn_fwd<<<dim3(16, 16, 2), 256, 0, stream>>>(Qb, Kb, Vt, doc, dstab, attout);
  gemm_bt<true><<<dim3(2048 / 128, 4096 / 128), 256, 0, stream>>>(attout, WoT, (float*)d_out, 4096, 2048, 2048);
}

// Round 7
// 255.531 us; speedup vs baseline: 1.9492x; 1.0169x over previous
//
#include <hip/hip_runtime.h>
#include <cstdint>
#include <cstddef>

typedef unsigned short u16;
typedef __attribute__((ext_vector_type(4))) float f32x4;
typedef __attribute__((ext_vector_type(8))) short bf16x8;

#define AS1 __attribute__((address_space(1)))
#define AS3 __attribute__((address_space(3)))
#define GLDS16(gp, lp) __builtin_amdgcn_global_load_lds((const AS1 void*)(gp), (AS3 void*)(lp), 16, 0, 0)

__device__ __forceinline__ float b2f(u16 u) {
  union { uint32_t i; float f; } v; v.i = ((uint32_t)u) << 16; return v.f;
}
__device__ __forceinline__ u16 f2b(float f) {
  union { float f; uint32_t i; } v; v.f = f;
  uint32_t r = v.i + 0x7fffu + ((v.i >> 16) & 1u);
  return (u16)(r >> 16);
}

// ---------------- fp32 -> bf16 elementwise convert (float4 vectorized) ------
__global__ __launch_bounds__(256) void cvt_f32_bf16(
    const float* __restrict__ in, u16* __restrict__ out, int n4) {
  int i = blockIdx.x * 256 + threadIdx.x;
  if (i >= n4) return;
  float4 v = ((const float4*)in)[i];
  union { u16 s[4]; uint2 u; } o;
  o.s[0] = f2b(v.x); o.s[1] = f2b(v.y); o.s[2] = f2b(v.z); o.s[3] = f2b(v.w);
  ((uint2*)out)[i] = o.u;
}

// ---------------- transpose + convert: out[c][r] = bf16(in[r][c]) -----------
__global__ __launch_bounds__(256) void transpose_f32_bf16(
    const float* __restrict__ in, u16* __restrict__ out, int R, int C) {
  __shared__ u16 t[32][33];
  int bx = blockIdx.x * 32;  // col base
  int by = blockIdx.y * 32;  // row base
  int tx = threadIdx.x & 31, ty = threadIdx.x >> 5;  // ty 0..7
#pragma unroll
  for (int i = 0; i < 4; ++i) {
    int r = by + ty + i * 8;
    t[ty + i * 8][tx] = f2b(in[(size_t)r * C + bx + tx]);
  }
  __syncthreads();
#pragma unroll
  for (int i = 0; i < 4; ++i) {
    int c = bx + ty + i * 8;
    out[(size_t)c * R + by + tx] = t[tx][ty + i * 8];
  }
}

// ---------------- doc start table: ds[b*4+d] = first s with doc==d ----------
__global__ __launch_bounds__(256) void doc_starts(
    const int* __restrict__ doc, int* __restrict__ ds) {
  int i = blockIdx.x * 256 + threadIdx.x;  // 0..4095
  if (i >= 4096) return;
  int b = i >> 11, s = i & 2047;
  int d = doc[i];
  if (s == 0 || doc[i - 1] != d) atomicMin(&ds[b * 4 + d], s);
}

// ---------------- GEMM: C(MxN) = A(MxK) * Bt(NxK)^T, bf16 in, f32 acc -------
// Output bf16 (F32OUT=false) or fp32 (F32OUT=true).
// 128x128 tile, BK=32, 4 waves (2x2), 64x64 per wave, 16x16x32 MFMA.
template <bool F32OUT>
__global__ __launch_bounds__(256) void gemm_bt(
    const u16* __restrict__ A, const u16* __restrict__ Bt, void* __restrict__ Cv,
    int M, int N, int K) {
  __shared__ __align__(16) u16 lA[128 * 32];
  __shared__ __align__(16) u16 lB[128 * 32];
  const int tid = threadIdx.x;
  const int lane = tid & 63, wv = tid >> 6;
  const int g = lane >> 4, lr = lane & 15;
  const int wr = wv >> 1, wc = wv & 1;
  const int bm0 = blockIdx.y * 128, bn0 = blockIdx.x * 128;
  f32x4 acc[4][4] = {};
  const int sr = tid >> 2;          // staging row 0..63
  const int scb = (tid & 3) * 16;   // staging byte col in 64B row
  const u16* ga = A + (size_t)(bm0 + sr) * K + (scb >> 1);
  const u16* gb = Bt + (size_t)(bn0 + sr) * K + (scb >> 1);
  char* dA = (char*)lA + tid * 16;
  char* dB = (char*)lB + tid * 16;
  for (int kt = 0; kt < K; kt += 32) {
    GLDS16(ga + kt, dA);
    GLDS16(ga + (size_t)64 * K + kt, dA + 4096);
    GLDS16(gb + kt, dB);
    GLDS16(gb + (size_t)64 * K + kt, dB + 4096);
    __syncthreads();
    bf16x8 af[4], bfr[4];
#pragma unroll
    for (int m = 0; m < 4; ++m)
      af[m] = *(const bf16x8*)((const char*)lA + (wr * 64 + m * 16 + lr) * 64 + g * 16);
#pragma unroll
    for (int n = 0; n < 4; ++n)
      bfr[n] = *(const bf16x8*)((const char*)lB + (wc * 64 + n * 16 + lr) * 64 + g * 16);
#pragma unroll
    for (int m = 0; m < 4; ++m)
#pragma unroll
      for (int n = 0; n < 4; ++n)
        acc[m][n] = __builtin_amdgcn_mfma_f32_16x16x32_bf16(af[m], bfr[n], acc[m][n], 0, 0, 0);
    __syncthreads();
  }
#pragma unroll
  for (int m = 0; m < 4; ++m)
#pragma unroll
    for (int r = 0; r < 4; ++r) {
      int row = bm0 + wr * 64 + m * 16 + g * 4 + r;
      int col = bn0 + wc * 64 + lr;
      if (F32OUT) {
        float* cp = (float*)Cv + (size_t)row * N + col;
#pragma unroll
        for (int n = 0; n < 4; ++n) cp[n * 16] = acc[m][n][r];
      } else {
        u16* cp = (u16*)Cv + (size_t)row * N + col;
#pragma unroll
        for (int n = 0; n < 4; ++n) cp[n * 16] = f2b(acc[m][n][r]);
      }
    }
}

// ---------------- RoPE + split into Q / K / V^T ----------------
// qkv: (4096 rows) x 3072 bf16. Q: [B][16][S][128]; K: [B][4][S][128];
// Vt: [B][4][128][S]. sin/cos fp32 [S][64].
__global__ __launch_bounds__(256) void rope_split(
    const u16* __restrict__ qkv, const float* __restrict__ sinb,
    const float* __restrict__ cosb, u16* __restrict__ Q, u16* __restrict__ Kb,
    u16* __restrict__ Vt) {
  int row = blockIdx.x;  // 0..4095
  int b = row >> 11, s = row & 2047;
  const u16* src = qkv + (size_t)row * 3072;
  __shared__ float scs[64], scc[64];
  if (threadIdx.x < 64) {
    scs[threadIdx.x] = sinb[s * 64 + threadIdx.x];
    scc[threadIdx.x] = cosb[s * 64 + threadIdx.x];
  }
  __syncthreads();
  int tid = threadIdx.x;
  // Q: 16 heads x 64 pairs
  for (int i = tid; i < 1024; i += 256) {
    int h = i >> 6, d = i & 63;
    float x1 = b2f(src[h * 128 + d]);
    float x2 = b2f(src[h * 128 + 64 + d]);
    size_t o = ((size_t)(b * 16 + h) * 2048 + s) * 128 + d;
    Q[o] = f2b(x1 * scc[d] - x2 * scs[d]);
    Q[o + 64] = f2b(x2 * scc[d] + x1 * scs[d]);
  }
  // K: 4 heads x 64 pairs (exactly 256 work items)
  {
    int i = tid;
    int g2 = i >> 6, d = i & 63;
    float x1 = b2f(src[2048 + g2 * 128 + d]);
    float x2 = b2f(src[2048 + g2 * 128 + 64 + d]);
    size_t o = ((size_t)(b * 4 + g2) * 2048 + s) * 128 + d;
    Kb[o] = f2b(x1 * scc[d] - x2 * scs[d]);
    Kb[o + 64] = f2b(x2 * scc[d] + x1 * scs[d]);
  }
  // V transposed copy: 512 elems
  for (int i = tid; i < 512; i += 256) {
    int g2 = i >> 7, d = i & 127;
    Vt[((size_t)(b * 4 + g2) * 128 + d) * 2048 + s] = src[2560 + g2 * 128 + d];
  }
}

// ---------------- Flash attention with causal + doc mask ----------------
// grid: (32, H, B): one block per 64-row q-tile (4 blocks/CU -> 50% occ cap).
// Doc-sorted skip: kv tiles before the tile's first doc start are skipped.
// block 256 = 4 waves; wave handles 16 q rows; KV block 32.
// K in LDS: linear dest, XOR-swizzled content (chunk ^= row&7), conflict-free.
// V/P in LDS: 80B padded rows, conflict-free.
// Online softmax with defer-max (THR=8): m only updated when it grows by >8;
// P bounded by e^8, f32 accum absorbs it. mrow init -1e30 keeps exp() NaN-free.
__global__ __launch_bounds__(256) void attn_fwd(
    const u16* __restrict__ Q, const u16* __restrict__ Kb,
    const u16* __restrict__ Vt, const int* __restrict__ doc,
    const int* __restrict__ dstab, u16* __restrict__ Out) {
  const int qb = blockIdx.x, h = blockIdx.y, b = blockIdx.z;
  const int gkv = h >> 2;
  const int tid = threadIdx.x, wv = tid >> 6, lane = tid & 63;
  const int g = lane >> 4, lr = lane & 15;
  const float scale = 0.08838834764831845f;  // 1/sqrt(128)
  __shared__ __align__(16) u16 Kl[32 * 128];   // [kv][d], swizzled chunks
  __shared__ __align__(16) u16 Vl[128 * 40];   // [d][kv], 80B rows (64B+16B pad)
  __shared__ __align__(16) u16 Pl[4][16 * 40]; // per-wave P, 80B rows
  const u16* Kbase = Kb + (size_t)(b * 4 + gkv) * 2048 * 128;
  const u16* Vbase = Vt + (size_t)(b * 4 + gkv) * 128 * 2048;
  const int b2048 = b * 2048;

  const int q0 = qb * 64 + wv * 16;
  // Q fragments (A): lane holds Q[q0+lr][32c + 8g .. +8]
  const u16* qp = Q + ((size_t)(b * 16 + h) * 2048 + q0 + lr) * 128;
  bf16x8 qf[4];
#pragma unroll
  for (int c = 0; c < 4; ++c) qf[c] = *(const bf16x8*)(qp + c * 32 + g * 8);
  int docq[4];
#pragma unroll
  for (int r = 0; r < 4; ++r) docq[r] = doc[b2048 + q0 + g * 4 + r];
  float mrow[4] = {-1e30f, -1e30f, -1e30f, -1e30f};
  float lrow[4] = {0.f, 0.f, 0.f, 0.f};
  f32x4 acc[8] = {};
  // doc-sorted skip: all kv < start(doc of block's first row) are masked
  const int kv_lo = dstab[b * 4 + doc[b2048 + qb * 64]] & ~31;
  const int kv_end = qb * 64 + 64;
  for (int kv0 = kv_lo; kv0 < kv_end; kv0 += 32) {
    // --- stage K (32x128) via global_load_lds, source pre-swizzled ---
#pragma unroll
    for (int it = 0; it < 2; ++it) {
      int ch = tid + it * 256;
      int kr = ch >> 4, j = ch & 15;  // row, 16B-chunk
      GLDS16(Kbase + (size_t)(kv0 + kr) * 128 + ((j ^ (kr & 7)) << 3),
             (char*)Kl + ch * 16);
    }
    // --- stage V (128d x 32kv) via regs into padded LDS ---
    bf16x8 vreg[2];
#pragma unroll
    for (int it = 0; it < 2; ++it) {
      int unit = tid + it * 256;
      int d = unit >> 2, c = unit & 3;
      vreg[it] = *(const bf16x8*)(Vbase + (size_t)d * 2048 + kv0 + c * 8);
    }
#pragma unroll
    for (int it = 0; it < 2; ++it) {
      int unit = tid + it * 256;
      int d = unit >> 2, c = unit & 3;
      *(bf16x8*)((char*)Vl + d * 80 + c * 16) = vreg[it];
    }
    __syncthreads();
    // --- scores: two 16-kv halves, swizzled K reads ---
    f32x4 s0 = {0.f, 0.f, 0.f, 0.f}, s1 = {0.f, 0.f, 0.f, 0.f};
    __builtin_amdgcn_s_setprio(1);
#pragma unroll
    for (int c = 0; c < 4; ++c) {
      int chnk = ((c * 4 + g) ^ (lr & 7)) << 4;
      bf16x8 k0 = *(const bf16x8*)((const char*)Kl + lr * 256 + chnk);
      s0 = __builtin_amdgcn_mfma_f32_16x16x32_bf16(qf[c], k0, s0, 0, 0, 0);
      bf16x8 k1 = *(const bf16x8*)((const char*)Kl + (16 + lr) * 256 + chnk);
      s1 = __builtin_amdgcn_mfma_f32_16x16x32_bf16(qf[c], k1, s1, 0, 0, 0);
    }
    __builtin_amdgcn_s_setprio(0);
    int dockv0 = doc[b2048 + kv0 + lr];
    int dockv1 = doc[b2048 + kv0 + 16 + lr];
#pragma unroll
    for (int r = 0; r < 4; ++r) {
      const int sq = q0 + g * 4 + r;
      int kva = kv0 + lr, kvb = kv0 + 16 + lr;
      float sa = (kva <= sq && dockv0 == docq[r]) ? s0[r] * scale : -INFINITY;
      float sb = (kvb <= sq && dockv1 == docq[r]) ? s1[r] * scale : -INFINITY;
      float rm = fmaxf(sa, sb);
#pragma unroll
      for (int off = 1; off < 16; off <<= 1) rm = fmaxf(rm, __shfl_xor(rm, off, 64));
      // defer-max: only rescale when max grows by more than THR=8
      if (rm > mrow[r] + 8.0f) {
        float scf = __expf(mrow[r] - rm);
        mrow[r] = rm;
        lrow[r] *= scf;
#pragma unroll
        for (int chn = 0; chn < 8; ++chn) acc[chn][r] *= scf;
      }
      float pa = __expf(sa - mrow[r]);
      float pb = __expf(sb - mrow[r]);
      float psum = pa + pb;
#pragma unroll
      for (int off = 1; off < 16; off <<= 1) psum += __shfl_xor(psum, off, 64);
      lrow[r] += psum;
      Pl[wv][(g * 4 + r) * 40 + lr] = f2b(pa);
      Pl[wv][(g * 4 + r) * 40 + 16 + lr] = f2b(pb);
    }
    asm volatile("s_waitcnt lgkmcnt(0)" ::: "memory");
    // PV: A = P[16x32], B = V chunk [32 kv x 16 d] from padded Vl[d][kv]
    bf16x8 pf = *(const bf16x8*)((const u16*)Pl[wv] + lr * 40 + g * 8);
    __builtin_amdgcn_s_setprio(1);
#pragma unroll
    for (int chn = 0; chn < 8; ++chn) {
      bf16x8 vf = *(const bf16x8*)((const char*)Vl + (chn * 16 + lr) * 80 + g * 16);
      acc[chn] = __builtin_amdgcn_mfma_f32_16x16x32_bf16(pf, vf, acc[chn], 0, 0, 0);
    }
    __builtin_amdgcn_s_setprio(0);
    __syncthreads();
  }
  // epilogue: Out[b][s][h*128 + d]
#pragma unroll
  for (int r = 0; r < 4; ++r) {
    float inv = 1.0f / lrow[r];
    int sq = q0 + g * 4 + r;
    u16* op = Out + ((size_t)b2048 + sq) * 2048 + h * 128 + lr;
#pragma unroll
    for (int chn = 0; chn < 8; ++chn) op[chn * 16] = f2b(acc[chn][r] * inv);
  }
}

extern "C" void kernel_launch(void* const* d_in, const int* in_sizes, int n_in,
                              void* d_out, int out_size, void* d_ws, size_t ws_size,
                              hipStream_t stream) {
  const float* x = (const float*)d_in[0];
  const float* sinb = (const float*)d_in[1];
  const float* cosb = (const float*)d_in[2];
  const int* doc = (const int*)d_in[3];
  const float* Wqkv = (const float*)d_in[4];
  const float* Wo = (const float*)d_in[5];

  u16* ws = (u16*)d_ws;
  u16* xb = ws;                             // 8,388,608
  u16* attout = xb;                         // reuse after GEMM1
  u16* WqkvT = ws + 8388608;                // 6,291,456
  u16* WoT = WqkvT;                         // reuse after GEMM1
  u16* qkv = WqkvT + 6291456;               // 12,582,912
  u16* Qb = qkv + 12582912;                 // 8,388,608
  u16* Kb = Qb + 8388608;                   // 2,097,152
  u16* Vt = Kb + 2097152;                   // 2,097,152
  int* dstab = (int*)(ws + 39845888);       // 8 ints
  // total: ~79.7 MB + 32B

  hipMemsetAsync(dstab, 0x7f, 8 * sizeof(int), stream);
  doc_starts<<<16, 256, 0, stream>>>(doc, dstab);
  cvt_f32_bf16<<<8388608 / 4 / 256, 256, 0, stream>>>(x, xb, 8388608 / 4);
  transpose_f32_bf16<<<dim3(3072 / 32, 2048 / 32), 256, 0, stream>>>(Wqkv, WqkvT, 2048, 3072);
  gemm_bt<false><<<dim3(3072 / 128, 4096 / 128), 256, 0, stream>>>(xb, WqkvT, qkv, 4096, 3072, 2048);
  transpose_f32_bf16<<<dim3(2048 / 32, 2048 / 32), 256, 0, stream>>>(Wo, WoT, 2048, 2048);
  rope_split<<<4096, 256, 0, stream>>>(qkv, sinb, cosb, Qb, Kb, Vt);
  attn_fwd<<<dim3(32, 16, 2), 256, 0, stream>>>(Qb, Kb, Vt, doc, dstab, attout);
  gemm_bt<true><<<dim3(2048 / 128, 4096 / 128), 256, 0, stream>>>(attout, WoT, (float*)d_out, 4096, 2048, 2048);
}